// Round 7
// baseline (218.297 us; speedup 1.0000x reference)
//
#include <hip/hip_runtime.h>
#include <hip/hip_bf16.h>

// Problem constants
#define N_ROWS 8192
#define D_DIM  1024
#define HALF_N 4096
#define N_TILES 2080             // 64*65/2 upper-triangular 128x128 tile pairs
#define N_RED  8                 // parallel loss-reduction blocks
constexpr float INV_T = 1.0f / 0.07f;   // 14.2857143 — also the fixed softmax max M

typedef __attribute__((ext_vector_type(4)))  float f32x4;
typedef __attribute__((ext_vector_type(16))) float f32x16;
typedef __attribute__((ext_vector_type(4)))  int   i32x4;
typedef __attribute__((ext_vector_type(8)))  int   i32x8;

// pack 4 floats -> 4 OCP e4m3 bytes in one dword
__device__ __forceinline__ unsigned int pk_fp8x4(float a, float b, float c, float d) {
    int v = __builtin_amdgcn_cvt_pk_fp8_f32(a, b, 0, false);   // bytes 0,1
    v = __builtin_amdgcn_cvt_pk_fp8_f32(c, d, v, true);        // bytes 2,3
    return (unsigned int)v;
}

// two global dwordx4 loads -> one v8i32 MX fragment (32 contiguous fp8 / lane)
__device__ __forceinline__ i32x8 ld_g32(const unsigned char* p) {
    i32x4 L = *(const i32x4*)p;
    i32x4 H = *(const i32x4*)(p + 16);
    i32x8 r;
    r[0] = L[0]; r[1] = L[1]; r[2] = L[2]; r[3] = L[3];
    r[4] = H[0]; r[5] = H[1]; r[6] = H[2]; r[7] = H[3];
    return r;
}

// MX-scaled fp8 MFMA, scales fixed at e8m0 0x7F = 2^0 = 1.0 (exact fp8 product,
// 2x the non-scaled fp8 rate). fmtA=fmtB=0 (OCP e4m3). Validated r21 (passed).
#define MXMFMA(AF, BF, ACC) ACC = __builtin_amdgcn_mfma_scale_f32_32x32x64_f8f6f4( \
        AF, BF, ACC, 0, 0, 0, 0x7F7F7F7F, 0, 0x7F7F7F7F)

// ---------------------------------------------------------------------------
// Kernel 1: row norms + fp8 e4m3 normalized copy + zeroing of row_sum and the
// handshake cells. One wave per row. (unchanged — measured fine)
__global__ __launch_bounds__(256) void norm_kernel(const float* __restrict__ feat,
                                                   unsigned char* __restrict__ fn8,
                                                   float* __restrict__ row_sum,
                                                   unsigned int* __restrict__ done_cnt,
                                                   unsigned int* __restrict__ fin_cnt,
                                                   float* __restrict__ loss_acc) {
    const int w = threadIdx.x >> 6, lane = threadIdx.x & 63;
    const int row = blockIdx.x * 4 + w;
    if (blockIdx.x == 0 && threadIdx.x == 0) {
        *done_cnt = 0u;
        *fin_cnt = 0u;
        *loss_acc = 0.f;
    }
    const float4* src = (const float4*)(feat + (size_t)row * D_DIM);
    float4 v[4];
    float ss = 0.f;
#pragma unroll
    for (int t = 0; t < 4; ++t) {
        v[t] = src[lane + 64 * t];
        ss += v[t].x * v[t].x + v[t].y * v[t].y + v[t].z * v[t].z + v[t].w * v[t].w;
    }
#pragma unroll
    for (int off = 32; off; off >>= 1) ss += __shfl_xor(ss, off);
    float nrm = fmaxf(sqrtf(ss), 1e-8f);
    if (lane == 0) row_sum[row] = 0.f;
    const float inv = 1.0f / nrm;
    unsigned int* dst = (unsigned int*)(fn8 + (size_t)row * D_DIM);
#pragma unroll
    for (int t = 0; t < 4; ++t)
        dst[lane + 64 * t] = pk_fp8x4(v[t].x * inv, v[t].y * inv, v[t].z * inv, v[t].w * inv);
}

// ---------------------------------------------------------------------------
// Kernel 2 (r24): ZERO-STAGING MX-fp8 triangular GEMM.
//
// Diagnosis across r16..r23: halving MFMA cycles (r21) moved duration ZERO;
// every LDS/pipeline variant (r19/r22/r23) lost by trading occupancy; no
// throughput resource is near ceiling (HBM 13%, L2 ~20%, MfmaUtil 17%).
// The ~60 us scaffold IS the staging: gload_lds issue + vmcnt(0) drains +
// barriers + ds_reads + the invariant 4.26M LDS conflict-cycles.
//
// fn8 is 8 MiB = L2/L3-resident. Guide common-mistake #7: don't LDS-stage
// what the cache already holds. Each lane's MFMA operand is 32 CONTIGUOUS
// bytes of one row -> two direct global_load_dwordx4.
// Line economics: lanes l and l+32 consume complementary 32B halves of the
// same 64B line within one instruction pair -> every line fetched once,
// fully used, no overfetch, no reuse window needed.
//
//  * NO LDS, NO barriers, NO drains, NO swizzle in the K-loop
//  * per wave: 16 iters x {8 global_load_dwordx4 -> 4 MXMFMA}; waves
//    free-run, cross-wave overlap hides the ~300cy L2 latency
//  * #pragma unroll 1 + __launch_bounds__(256,4): VGPR <= 128 (r22 lesson),
//    4 waves/SIMD
//  * epilogue (32x32 C/D layout) + fence-free loss tail verbatim from r21
__global__ __launch_bounds__(256, 4) void simgemm_kernel(const unsigned char* __restrict__ fn8,
                                                         float* __restrict__ row_sum,
                                                         float* __restrict__ s_target,
                                                         unsigned int* __restrict__ done_cnt,
                                                         unsigned int* __restrict__ fin_cnt,
                                                         float* __restrict__ loss_acc,
                                                         float* __restrict__ out) {
    // triangular decode: t -> (I,J), I<=J
    const int t = blockIdx.x;
    int a = (int)((sqrtf(8.f * (float)t + 1.f) - 1.f) * 0.5f);
    while ((a + 1) * (a + 2) / 2 <= t) ++a;
    while (a * (a + 1) / 2 > t) --a;
    const int I = t - a * (a + 1) / 2;   // row-tile index (<= J)
    const int J = a;                     // col-tile index
    const int r0 = I * 128, c0 = J * 128;
    const bool isdiag = (I == J);
    const bool haspair = (J == I + 32);  // contains sim[i, i+4096] for rows in I

    const int tid = threadIdx.x;
    const int w = tid >> 6, lane = tid & 63;
    const int wr = (w >> 1) * 64;  // wave's row base within tile
    const int wc = (w & 1) * 64;   // wave's col base within tile

    // ---- direct-global fragment addressing ----
    // lane (fr, h): row base + fr, K-bytes [kk*64 + h*32, +32)
    const int fr = lane & 31;
    const int h = lane >> 5;
    const unsigned char* gA0 = fn8 + (size_t)(r0 + wr + 0  + fr) * D_DIM + h * 32;
    const unsigned char* gA1 = fn8 + (size_t)(r0 + wr + 32 + fr) * D_DIM + h * 32;
    const unsigned char* gB0 = fn8 + (size_t)(c0 + wc + 0  + fr) * D_DIM + h * 32;
    const unsigned char* gB1 = fn8 + (size_t)(c0 + wc + 32 + fr) * D_DIM + h * 32;

    f32x16 acc[2][2] = {};

#pragma unroll 1
    for (int kk = 0; kk < 16; ++kk) {
        const int ko = kk * 64;
        i32x8 a0 = ld_g32(gA0 + ko);
        i32x8 a1 = ld_g32(gA1 + ko);
        i32x8 b0 = ld_g32(gB0 + ko);
        i32x8 b1 = ld_g32(gB1 + ko);
        __builtin_amdgcn_s_setprio(1);
        MXMFMA(a0, b0, acc[0][0]);
        MXMFMA(a0, b1, acc[0][1]);
        MXMFMA(a1, b0, acc[1][0]);
        MXMFMA(a1, b1, acc[1][1]);
        __builtin_amdgcn_s_setprio(0);
    }

    // ---- epilogue: e = exp(sim - M); rows-in-I sums + (I<J) cols-in-J sums ----
    // 32x32 C/D layout: col = c0 + wc + tj*32 + (lane&31),
    //                   row = r0 + wr + ti*32 + (reg&3) + 8*(reg>>2) + 4*h
    const int colL = lane & 31;
    float cs[2] = {0.f, 0.f};
#pragma unroll
    for (int ti = 0; ti < 2; ++ti) {
#pragma unroll
        for (int reg = 0; reg < 16; ++reg) {
            const int rowL = (reg & 3) + 8 * (reg >> 2) + 4 * h;
            const int grow = r0 + wr + ti * 32 + rowL;
            float s = 0.f;
#pragma unroll
            for (int tj = 0; tj < 2; ++tj) {
                const int gcol = c0 + wc + tj * 32 + colL;
                float sim = acc[ti][tj][reg] * INV_T;
                float e = __expf(sim - INV_T);
                if (isdiag && grow == gcol) e = 0.f;   // diagonal mask
                if (haspair && gcol == grow + HALF_N) {
                    __hip_atomic_store(&s_target[grow], sim, __ATOMIC_RELAXED,
                                       __HIP_MEMORY_SCOPE_AGENT);
                    __hip_atomic_store(&s_target[gcol], sim, __ATOMIC_RELAXED,
                                       __HIP_MEMORY_SCOPE_AGENT);
                }
                s += e;
                cs[tj] += e;
            }
            // row path: reduce across the 32 column-lanes of this h-group
            s += __shfl_xor(s, 1);
            s += __shfl_xor(s, 2);
            s += __shfl_xor(s, 4);
            s += __shfl_xor(s, 8);
            s += __shfl_xor(s, 16);
            if (colL == 0) atomicAdd(&row_sum[grow], s);
        }
    }
    if (!isdiag) {
        // col path: lane l holds 32 of the wave's 64 rows for its column;
        // pair with lane l^32 (other h) to complete, one atomic per column
#pragma unroll
        for (int tj = 0; tj < 2; ++tj) {
            float s = cs[tj] + __shfl_xor(cs[tj], 32);
            if (h == 0) atomicAdd(&row_sum[c0 + wc + tj * 32 + colL], s);
        }
    }

    // ---- fence-free fused loss tail, 8-way parallel ----
    __syncthreads();   // all waves' vmem drained (compiler emits vmcnt(0) here)
    __shared__ unsigned int my_ord;
    if (tid == 0)
        my_ord = __hip_atomic_fetch_add(done_cnt, 1u, __ATOMIC_RELAXED,
                                        __HIP_MEMORY_SCOPE_AGENT);
    __syncthreads();
    const unsigned int ord = my_ord;
    if (ord >= N_TILES - N_RED) {
        // wait until ALL 2080 blocks have signalled (their sums are in).
        if (tid == 0) {
            while (__hip_atomic_load(done_cnt, __ATOMIC_RELAXED,
                                     __HIP_MEMORY_SCOPE_AGENT) < N_TILES)
                __builtin_amdgcn_s_sleep(1);
        }
        __syncthreads();
        const int slice = (int)(ord - (N_TILES - N_RED));   // 0..7
        const int base_row = slice * (N_ROWS / N_RED) + tid * 4;
        float rv[4], sv[4];
#pragma unroll
        for (int u = 0; u < 4; ++u) {
            rv[u] = __hip_atomic_load(&row_sum[base_row + u], __ATOMIC_RELAXED,
                                      __HIP_MEMORY_SCOPE_AGENT);
            sv[u] = __hip_atomic_load(&s_target[base_row + u], __ATOMIC_RELAXED,
                                      __HIP_MEMORY_SCOPE_AGENT);
        }
        float local = 0.f;
#pragma unroll
        for (int u = 0; u < 4; ++u)
            local += __logf(rv[u]) - sv[u];
#pragma unroll
        for (int off = 32; off; off >>= 1) local += __shfl_xor(local, off);
        __shared__ float part[4];
        if ((tid & 63) == 0) part[tid >> 6] = local;
        __syncthreads();
        if (tid == 0) {
            float bsum = part[0] + part[1] + part[2] + part[3];
            __hip_atomic_fetch_add(loss_acc, bsum, __ATOMIC_RELAXED,
                                   __HIP_MEMORY_SCOPE_AGENT);
            unsigned int f = __hip_atomic_fetch_add(fin_cnt, 1u, __ATOMIC_ACQ_REL,
                                                    __HIP_MEMORY_SCOPE_AGENT);
            if (f == N_RED - 1) {
                float accv = __hip_atomic_load(loss_acc, __ATOMIC_RELAXED,
                                               __HIP_MEMORY_SCOPE_AGENT);
                out[0] = INV_T + accv * (1.0f / N_ROWS);
            }
        }
    }
}

// ---------------------------------------------------------------------------
extern "C" void kernel_launch(void* const* d_in, const int* in_sizes, int n_in,
                              void* d_out, int out_size, void* d_ws, size_t ws_size,
                              hipStream_t stream) {
    const float* feat = (const float*)d_in[0];
    float* out = (float*)d_out;
    char* ws = (char*)d_ws;

    unsigned char* fn8 = (unsigned char*)ws;                  // 8192*1024 fp8 = 8 MiB
    size_t off = (size_t)N_ROWS * D_DIM;
    float* row_sum = (float*)(ws + off);   off += N_ROWS * sizeof(float);
    float* s_target = (float*)(ws + off);  off += N_ROWS * sizeof(float);
    unsigned int* done_cnt = (unsigned int*)(ws + off);  off += sizeof(unsigned int);
    unsigned int* fin_cnt = (unsigned int*)(ws + off);   off += sizeof(unsigned int);
    float* loss_acc = (float*)(ws + off);

    norm_kernel<<<N_ROWS / 4, 256, 0, stream>>>(feat, fn8, row_sum, done_cnt, fin_cnt, loss_acc);
    simgemm_kernel<<<N_TILES, 256, 0, stream>>>(fn8, row_sum, s_target, done_cnt, fin_cnt, loss_acc, out);
}

// Round 8
// 216.372 us; speedup vs baseline: 1.0089x; 1.0089x over previous
//
#include <hip/hip_runtime.h>
#include <hip/hip_bf16.h>

// Problem constants
#define N_ROWS 8192
#define D_DIM  1024
#define HALF_N 4096
#define N_TILES 2080             // 64*65/2 upper-triangular 128x128 tile pairs
#define N_RED  8                 // parallel loss-reduction blocks
constexpr float INV_T = 1.0f / 0.07f;   // 14.2857143 — also the fixed softmax max M

typedef __attribute__((ext_vector_type(4)))  float f32x4;
typedef __attribute__((ext_vector_type(16))) float f32x16;
typedef __attribute__((ext_vector_type(4)))  int   i32x4;
typedef __attribute__((ext_vector_type(8)))  int   i32x8;

// pack 4 floats -> 4 OCP e4m3 bytes in one dword
__device__ __forceinline__ unsigned int pk_fp8x4(float a, float b, float c, float d) {
    int v = __builtin_amdgcn_cvt_pk_fp8_f32(a, b, 0, false);   // bytes 0,1
    v = __builtin_amdgcn_cvt_pk_fp8_f32(c, d, v, true);        // bytes 2,3
    return (unsigned int)v;
}

// two global dwordx4 loads -> one v8i32 MX fragment (32 contiguous fp8 / lane)
__device__ __forceinline__ i32x8 ld_g32(const unsigned char* p) {
    i32x4 L = *(const i32x4*)p;
    i32x4 H = *(const i32x4*)(p + 16);
    i32x8 r;
    r[0] = L[0]; r[1] = L[1]; r[2] = L[2]; r[3] = L[3];
    r[4] = H[0]; r[5] = H[1]; r[6] = H[2]; r[7] = H[3];
    return r;
}

// MX-scaled fp8 MFMA, scales fixed at e8m0 0x7F = 2^0 = 1.0 (exact fp8 product,
// 2x the non-scaled fp8 rate). fmtA=fmtB=0 (OCP e4m3). Validated r21/r24.
#define MXMFMA(AF, BF, ACC) ACC = __builtin_amdgcn_mfma_scale_f32_32x32x64_f8f6f4( \
        AF, BF, ACC, 0, 0, 0, 0x7F7F7F7F, 0, 0x7F7F7F7F)

// ---------------------------------------------------------------------------
// Kernel 1: row norms + fp8 e4m3 normalized copy + zeroing of row_sum and the
// handshake cells. One wave per row. (unchanged — measured fine)
__global__ __launch_bounds__(256) void norm_kernel(const float* __restrict__ feat,
                                                   unsigned char* __restrict__ fn8,
                                                   float* __restrict__ row_sum,
                                                   unsigned int* __restrict__ done_cnt,
                                                   unsigned int* __restrict__ fin_cnt,
                                                   float* __restrict__ loss_acc) {
    const int w = threadIdx.x >> 6, lane = threadIdx.x & 63;
    const int row = blockIdx.x * 4 + w;
    if (blockIdx.x == 0 && threadIdx.x == 0) {
        *done_cnt = 0u;
        *fin_cnt = 0u;
        *loss_acc = 0.f;
    }
    const float4* src = (const float4*)(feat + (size_t)row * D_DIM);
    float4 v[4];
    float ss = 0.f;
#pragma unroll
    for (int t = 0; t < 4; ++t) {
        v[t] = src[lane + 64 * t];
        ss += v[t].x * v[t].x + v[t].y * v[t].y + v[t].z * v[t].z + v[t].w * v[t].w;
    }
#pragma unroll
    for (int off = 32; off; off >>= 1) ss += __shfl_xor(ss, off);
    float nrm = fmaxf(sqrtf(ss), 1e-8f);
    if (lane == 0) row_sum[row] = 0.f;
    const float inv = 1.0f / nrm;
    unsigned int* dst = (unsigned int*)(fn8 + (size_t)row * D_DIM);
#pragma unroll
    for (int t = 0; t < 4; ++t)
        dst[lane + 64 * t] = pk_fp8x4(v[t].x * inv, v[t].y * inv, v[t].z * inv, v[t].w * inv);
}

// ---------------------------------------------------------------------------
// Kernel 2 (r25): direct-global MX-fp8 GEMM with 2-DEEP REGISTER PING-PONG.
//
// r24 post-mortem: zero-staging was latency-serialized (unroll 1, no
// prefetch: issue 8 loads -> stall ~300-600cy -> 276cy MFMA). Fix: named
// P/Q fragment register sets (STATIC indexing — rule #20: no runtime-indexed
// arrays), issue Q(k+1) BEFORE MFMA(P(k)); compiler's counted vmcnt(8)
// gives every load one full MFMA phase (~340cy) to land. No LDS, no
// barriers, no drains in the K-loop.
//
// Traffic floor: 2080 blocks x 512KB (A,B read by 2 waves each) = 1.06 GB
// from L2/L3 ~= 31 us at the 34.5 TB/s L2 ceiling — vs the LDS-staged
// structure's measured 77 us scaffold plateau (r16/r21 invariance).
//
//  * T1 XCD-aware swizzle (2080%8==0, bijective): consecutive tiles share
//    A-panels -> per-XCD chunks turn L3 traffic into local L2 hits
//  * __launch_bounds__(256,3): VGPR cap 170 (acc 64 + 2x32 frags + addr),
//    12 waves/CU
//  * epilogue (32x32 C/D layout) + fence-free loss tail verbatim from r24
__global__ __launch_bounds__(256, 3) void simgemm_kernel(const unsigned char* __restrict__ fn8,
                                                         float* __restrict__ row_sum,
                                                         float* __restrict__ s_target,
                                                         unsigned int* __restrict__ done_cnt,
                                                         unsigned int* __restrict__ fin_cnt,
                                                         float* __restrict__ loss_acc,
                                                         float* __restrict__ out) {
    // XCD-aware bijective swizzle: 8 XCDs x 260 contiguous tiles each
    const int t = (blockIdx.x & 7) * (N_TILES / 8) + (blockIdx.x >> 3);
    // triangular decode: t -> (I,J), I<=J
    int a = (int)((sqrtf(8.f * (float)t + 1.f) - 1.f) * 0.5f);
    while ((a + 1) * (a + 2) / 2 <= t) ++a;
    while (a * (a + 1) / 2 > t) --a;
    const int I = t - a * (a + 1) / 2;   // row-tile index (<= J)
    const int J = a;                     // col-tile index
    const int r0 = I * 128, c0 = J * 128;
    const bool isdiag = (I == J);
    const bool haspair = (J == I + 32);  // contains sim[i, i+4096] for rows in I

    const int tid = threadIdx.x;
    const int w = tid >> 6, lane = tid & 63;
    const int wr = (w >> 1) * 64;  // wave's row base within tile
    const int wc = (w & 1) * 64;   // wave's col base within tile

    // ---- direct-global fragment addressing ----
    // lane (fr, h): row base + fr, K-bytes [kk*64 + h*32, +32)
    const int fr = lane & 31;
    const int h = lane >> 5;
    const unsigned char* gA0 = fn8 + (size_t)(r0 + wr + 0  + fr) * D_DIM + h * 32;
    const unsigned char* gA1 = fn8 + (size_t)(r0 + wr + 32 + fr) * D_DIM + h * 32;
    const unsigned char* gB0 = fn8 + (size_t)(c0 + wc + 0  + fr) * D_DIM + h * 32;
    const unsigned char* gB1 = fn8 + (size_t)(c0 + wc + 32 + fr) * D_DIM + h * 32;

    f32x16 acc00 = {}, acc01 = {}, acc10 = {}, acc11 = {};

    // ---- 2-deep register ping-pong over 16 K-chunks ----
    i32x8 aP0, aP1, bP0, bP1, aQ0, aQ1, bQ0, bQ1;
    // prologue: P <- chunk 0
    aP0 = ld_g32(gA0);  aP1 = ld_g32(gA1);
    bP0 = ld_g32(gB0);  bP1 = ld_g32(gB1);

#define MFMA4(A0, A1, B0, B1) do {            \
    __builtin_amdgcn_s_setprio(1);            \
    MXMFMA(A0, B0, acc00);                    \
    MXMFMA(A0, B1, acc01);                    \
    MXMFMA(A1, B0, acc10);                    \
    MXMFMA(A1, B1, acc11);                    \
    __builtin_amdgcn_s_setprio(0);            \
} while (0)

#pragma unroll 1
    for (int kk = 0; kk < 14; kk += 2) {
        const int k1 = (kk + 1) * 64, k2 = (kk + 2) * 64;
        // issue Q(kk+1) before consuming P(kk): latency hides under MFMA4(P)
        aQ0 = ld_g32(gA0 + k1);  aQ1 = ld_g32(gA1 + k1);
        bQ0 = ld_g32(gB0 + k1);  bQ1 = ld_g32(gB1 + k1);
        MFMA4(aP0, aP1, bP0, bP1);
        // issue P(kk+2) before consuming Q(kk+1)
        aP0 = ld_g32(gA0 + k2);  aP1 = ld_g32(gA1 + k2);
        bP0 = ld_g32(gB0 + k2);  bP1 = ld_g32(gB1 + k2);
        MFMA4(aQ0, aQ1, bQ0, bQ1);
    }
    // tail: P holds chunk 14; load Q(15), consume both
    {
        const int k1 = 15 * 64;
        aQ0 = ld_g32(gA0 + k1);  aQ1 = ld_g32(gA1 + k1);
        bQ0 = ld_g32(gB0 + k1);  bQ1 = ld_g32(gB1 + k1);
        MFMA4(aP0, aP1, bP0, bP1);
        MFMA4(aQ0, aQ1, bQ0, bQ1);
    }
#undef MFMA4

    // ---- epilogue: e = exp(sim - M); rows-in-I sums + (I<J) cols-in-J sums ----
    // 32x32 C/D layout: col = c0 + wc + tj*32 + (lane&31),
    //                   row = r0 + wr + ti*32 + (reg&3) + 8*(reg>>2) + 4*h
    const int colL = lane & 31;
    float cs[2] = {0.f, 0.f};
#pragma unroll
    for (int ti = 0; ti < 2; ++ti) {
#pragma unroll
        for (int reg = 0; reg < 16; ++reg) {
            const int rowL = (reg & 3) + 8 * (reg >> 2) + 4 * h;
            const int grow = r0 + wr + ti * 32 + rowL;
            float s = 0.f;
#pragma unroll
            for (int tj = 0; tj < 2; ++tj) {
                const int gcol = c0 + wc + tj * 32 + colL;
                const f32x16& A = (ti == 0) ? ((tj == 0) ? acc00 : acc01)
                                            : ((tj == 0) ? acc10 : acc11);
                float sim = A[reg] * INV_T;
                float e = __expf(sim - INV_T);
                if (isdiag && grow == gcol) e = 0.f;   // diagonal mask
                if (haspair && gcol == grow + HALF_N) {
                    __hip_atomic_store(&s_target[grow], sim, __ATOMIC_RELAXED,
                                       __HIP_MEMORY_SCOPE_AGENT);
                    __hip_atomic_store(&s_target[gcol], sim, __ATOMIC_RELAXED,
                                       __HIP_MEMORY_SCOPE_AGENT);
                }
                s += e;
                cs[tj] += e;
            }
            // row path: reduce across the 32 column-lanes of this h-group
            s += __shfl_xor(s, 1);
            s += __shfl_xor(s, 2);
            s += __shfl_xor(s, 4);
            s += __shfl_xor(s, 8);
            s += __shfl_xor(s, 16);
            if (colL == 0) atomicAdd(&row_sum[grow], s);
        }
    }
    if (!isdiag) {
        // col path: lane l holds 32 of the wave's 64 rows for its column;
        // pair with lane l^32 (other h) to complete, one atomic per column
#pragma unroll
        for (int tj = 0; tj < 2; ++tj) {
            float s = cs[tj] + __shfl_xor(cs[tj], 32);
            if (h == 0) atomicAdd(&row_sum[c0 + wc + tj * 32 + colL], s);
        }
    }

    // ---- fence-free fused loss tail, 8-way parallel ----
    __syncthreads();   // all waves' vmem drained (compiler emits vmcnt(0) here)
    __shared__ unsigned int my_ord;
    if (tid == 0)
        my_ord = __hip_atomic_fetch_add(done_cnt, 1u, __ATOMIC_RELAXED,
                                        __HIP_MEMORY_SCOPE_AGENT);
    __syncthreads();
    const unsigned int ord = my_ord;
    if (ord >= N_TILES - N_RED) {
        // wait until ALL 2080 blocks have signalled (their sums are in).
        if (tid == 0) {
            while (__hip_atomic_load(done_cnt, __ATOMIC_RELAXED,
                                     __HIP_MEMORY_SCOPE_AGENT) < N_TILES)
                __builtin_amdgcn_s_sleep(1);
        }
        __syncthreads();
        const int slice = (int)(ord - (N_TILES - N_RED));   // 0..7
        const int base_row = slice * (N_ROWS / N_RED) + tid * 4;
        float rv[4], sv[4];
#pragma unroll
        for (int u = 0; u < 4; ++u) {
            rv[u] = __hip_atomic_load(&row_sum[base_row + u], __ATOMIC_RELAXED,
                                      __HIP_MEMORY_SCOPE_AGENT);
            sv[u] = __hip_atomic_load(&s_target[base_row + u], __ATOMIC_RELAXED,
                                      __HIP_MEMORY_SCOPE_AGENT);
        }
        float local = 0.f;
#pragma unroll
        for (int u = 0; u < 4; ++u)
            local += __logf(rv[u]) - sv[u];
#pragma unroll
        for (int off = 32; off; off >>= 1) local += __shfl_xor(local, off);
        __shared__ float part[4];
        if ((tid & 63) == 0) part[tid >> 6] = local;
        __syncthreads();
        if (tid == 0) {
            float bsum = part[0] + part[1] + part[2] + part[3];
            __hip_atomic_fetch_add(loss_acc, bsum, __ATOMIC_RELAXED,
                                   __HIP_MEMORY_SCOPE_AGENT);
            unsigned int f = __hip_atomic_fetch_add(fin_cnt, 1u, __ATOMIC_ACQ_REL,
                                                    __HIP_MEMORY_SCOPE_AGENT);
            if (f == N_RED - 1) {
                float accv = __hip_atomic_load(loss_acc, __ATOMIC_RELAXED,
                                               __HIP_MEMORY_SCOPE_AGENT);
                out[0] = INV_T + accv * (1.0f / N_ROWS);
            }
        }
    }
}

// ---------------------------------------------------------------------------
extern "C" void kernel_launch(void* const* d_in, const int* in_sizes, int n_in,
                              void* d_out, int out_size, void* d_ws, size_t ws_size,
                              hipStream_t stream) {
    const float* feat = (const float*)d_in[0];
    float* out = (float*)d_out;
    char* ws = (char*)d_ws;

    unsigned char* fn8 = (unsigned char*)ws;                  // 8192*1024 fp8 = 8 MiB
    size_t off = (size_t)N_ROWS * D_DIM;
    float* row_sum = (float*)(ws + off);   off += N_ROWS * sizeof(float);
    float* s_target = (float*)(ws + off);  off += N_ROWS * sizeof(float);
    unsigned int* done_cnt = (unsigned int*)(ws + off);  off += sizeof(unsigned int);
    unsigned int* fin_cnt = (unsigned int*)(ws + off);   off += sizeof(unsigned int);
    float* loss_acc = (float*)(ws + off);

    norm_kernel<<<N_ROWS / 4, 256, 0, stream>>>(feat, fn8, row_sum, done_cnt, fin_cnt, loss_acc);
    simgemm_kernel<<<N_TILES, 256, 0, stream>>>(fn8, row_sum, s_target, done_cnt, fin_cnt, loss_acc, out);
}

// Round 9
// 170.688 us; speedup vs baseline: 1.2789x; 1.2676x over previous
//
#include <hip/hip_runtime.h>
#include <hip/hip_bf16.h>

// Problem constants
#define N_ROWS 8192
#define D_DIM  1024
#define HALF_N 4096
#define N_TILES 2080             // 64*65/2 upper-triangular 128x128 tile pairs
#define N_RED  8                 // parallel loss-reduction blocks
#define N_PERS 1024              // persistent blocks (4/CU target)
constexpr float INV_T = 1.0f / 0.07f;   // 14.2857143 — also the fixed softmax max M

typedef __attribute__((ext_vector_type(4))) float f32x4;
typedef __attribute__((ext_vector_type(2))) long long2_;   // 16B = one ds_read_b128

// async global->LDS, 16B/lane. LDS dest is wave-uniform base + lane*16.
__device__ __forceinline__ void async_ld16(const void* g, void* lds) {
    __builtin_amdgcn_global_load_lds(
        (const __attribute__((address_space(1))) void*)g,
        (__attribute__((address_space(3))) void*)lds,
        16, 0, 0);
}

// pack 4 floats -> 4 OCP e4m3 bytes in one dword
__device__ __forceinline__ unsigned int pk_fp8x4(float a, float b, float c, float d) {
    int v = __builtin_amdgcn_cvt_pk_fp8_f32(a, b, 0, false);   // bytes 0,1
    v = __builtin_amdgcn_cvt_pk_fp8_f32(c, d, v, true);        // bytes 2,3
    return (unsigned int)v;
}

// ---------------------------------------------------------------------------
// Kernel 1: row norms + fp8 e4m3 normalized copy + zeroing of row_sum and the
// handshake cells (done_cnt, fin_cnt, loss_acc, tile_cnt). One wave per row.
__global__ __launch_bounds__(256) void norm_kernel(const float* __restrict__ feat,
                                                   unsigned char* __restrict__ fn8,
                                                   float* __restrict__ row_sum,
                                                   unsigned int* __restrict__ done_cnt,
                                                   unsigned int* __restrict__ fin_cnt,
                                                   float* __restrict__ loss_acc,
                                                   unsigned int* __restrict__ tile_cnt) {
    const int w = threadIdx.x >> 6, lane = threadIdx.x & 63;
    const int row = blockIdx.x * 4 + w;
    if (blockIdx.x == 0 && threadIdx.x == 0) {
        *done_cnt = 0u;
        *fin_cnt = 0u;
        *loss_acc = 0.f;
        *tile_cnt = 0u;
    }
    const float4* src = (const float4*)(feat + (size_t)row * D_DIM);
    float4 v[4];
    float ss = 0.f;
#pragma unroll
    for (int t = 0; t < 4; ++t) {
        v[t] = src[lane + 64 * t];
        ss += v[t].x * v[t].x + v[t].y * v[t].y + v[t].z * v[t].z + v[t].w * v[t].w;
    }
#pragma unroll
    for (int off = 32; off; off >>= 1) ss += __shfl_xor(ss, off);
    float nrm = fmaxf(sqrtf(ss), 1e-8f);
    if (lane == 0) row_sum[row] = 0.f;
    const float inv = 1.0f / nrm;
    unsigned int* dst = (unsigned int*)(fn8 + (size_t)row * D_DIM);
#pragma unroll
    for (int t = 0; t < 4; ++t)
        dst[lane + 64 * t] = pk_fp8x4(v[t].x * inv, v[t].y * inv, v[t].z * inv, v[t].w * inv);
}

// ---------------------------------------------------------------------------
// Kernel 2 (r26): the PROVEN r16 inner structure (77.3 us measured: fp8 e4m3
// 16x16x32 MFMA, 128^2 triangular tiles, BK=64, 2-barrier single-buffer loop,
// rotate-swizzle staging + K-permuted b128 fragment reads, 0 bank conflicts,
// VGPR 84) — UNCHANGED instruction-for-instruction — wrapped in a
// PERSISTENT-BLOCK WORK QUEUE:
//  * N_PERS=1024 blocks pop tiles from an atomic counter until empty.
//    Removes round/makespan quantization (fixed-assignment stragglers):
//    per-tile duration variance (diag vs pair tiles) now backfills.
//    Post-mortem r18-r25: every change to the K-loop itself regressed;
//    the queue is the only untouched loss term that composes with r16.
//  * per-tile done-counter + fence-free 8-way loss tail logic unchanged
//    (a block may execute several of the last-8 reduction slices
//    sequentially — ords are distinct, slices are distinct, fin_cnt exact).
__global__ __launch_bounds__(256) void simgemm_kernel(const unsigned char* __restrict__ fn8,
                                                      float* __restrict__ row_sum,
                                                      float* __restrict__ s_target,
                                                      unsigned int* __restrict__ done_cnt,
                                                      unsigned int* __restrict__ fin_cnt,
                                                      float* __restrict__ loss_acc,
                                                      unsigned int* __restrict__ tile_cnt,
                                                      float* __restrict__ out) {
    __shared__ __align__(16) unsigned char As[128 * 64];   // 8 KiB
    __shared__ __align__(16) unsigned char Bs[128 * 64];   // 8 KiB
    __shared__ unsigned int my_ord, next_t;

    const int tid = threadIdx.x;
    const int w = tid >> 6, lane = tid & 63;
    const int q = lane >> 4, c16 = lane & 15;
    const int wr = (w >> 1) * 64;  // wave's row base within tile
    const int wc = (w & 1) * 64;   // wave's col base within tile
    const int wr4 = (w >> 1) * 4;  // wave's A chunk base (16-row chunks)
    const int wc4 = (w & 1) * 4;   // wave's B chunk base
    // staging: wave w stages chunks 2w, 2w+1 (rows w*32 .. w*32+31).
    const int srow = lane >> 2;                               // row within chunk
    const int skoff = ((lane & 3) ^ ((srow >> 1) & 3)) * 16;  // swizzled unit byte offset
    // fragment read byte offset within a chunk (kt-invariant)
    const int lfo = c16 * 64 + ((q ^ ((c16 >> 1) & 3)) * 16);

    // pop first tile
    if (tid == 0)
        next_t = __hip_atomic_fetch_add(tile_cnt, 1u, __ATOMIC_RELAXED,
                                        __HIP_MEMORY_SCOPE_AGENT);
    __syncthreads();

    while (true) {
        const int t = (int)next_t;
        if (t >= N_TILES) break;                // uniform exit
        // triangular decode: t -> (I,J), I<=J
        int a = (int)((sqrtf(8.f * (float)t + 1.f) - 1.f) * 0.5f);
        while ((a + 1) * (a + 2) / 2 <= t) ++a;
        while (a * (a + 1) / 2 > t) --a;
        const int I = t - a * (a + 1) / 2;   // row-tile index (<= J)
        const int J = a;                     // col-tile index
        const int r0 = I * 128, c0 = J * 128;
        const bool isdiag = (I == J);
        const bool haspair = (J == I + 32);  // contains sim[i, i+4096]

        const unsigned char* pa0 = fn8 + (size_t)(r0 + w * 32 + srow) * D_DIM + skoff;
        const unsigned char* pa1 = pa0 + 16 * D_DIM;
        const unsigned char* pb0 = fn8 + (size_t)(c0 + w * 32 + srow) * D_DIM + skoff;
        const unsigned char* pb1 = pb0 + 16 * D_DIM;

        f32x4 acc[4][4];
#pragma unroll
        for (int i = 0; i < 4; ++i)
#pragma unroll
            for (int j = 0; j < 4; ++j) acc[i][j] = (f32x4){0.f, 0.f, 0.f, 0.f};

        for (int kt = 0; kt < 16; ++kt) {
            __syncthreads();  // previous window's reads (or prev tile) done
            async_ld16(pa0, (void*)&As[(w * 2 + 0) * 1024]);
            async_ld16(pa1, (void*)&As[(w * 2 + 1) * 1024]);
            async_ld16(pb0, (void*)&Bs[(w * 2 + 0) * 1024]);
            async_ld16(pb1, (void*)&Bs[(w * 2 + 1) * 1024]);
            pa0 += 64; pa1 += 64; pb0 += 64; pb1 += 64;
            __syncthreads();  // drains vmcnt(0): staging visible

            long2_ af[4], bf[4];
#pragma unroll
            for (int i = 0; i < 4; ++i)
                af[i] = *(const long2_*)&As[(wr4 + i) * 1024 + lfo];
#pragma unroll
            for (int j = 0; j < 4; ++j)
                bf[j] = *(const long2_*)&Bs[(wc4 + j) * 1024 + lfo];
#pragma unroll
            for (int i = 0; i < 4; ++i)
#pragma unroll
                for (int j = 0; j < 4; ++j) {
                    acc[i][j] = __builtin_amdgcn_mfma_f32_16x16x32_fp8_fp8(
                        af[i].x, bf[j].x, acc[i][j], 0, 0, 0);
                    acc[i][j] = __builtin_amdgcn_mfma_f32_16x16x32_fp8_fp8(
                        af[i].y, bf[j].y, acc[i][j], 0, 0, 0);
                }
        }

        // epilogue: e = exp(sim - M); rows-in-I sums + (I<J) cols-in-J sums.
        float cs[4] = {0.f, 0.f, 0.f, 0.f};
#pragma unroll
        for (int i = 0; i < 4; ++i) {
            const int growb = r0 + wr + i * 16 + q * 4;
#pragma unroll
            for (int r = 0; r < 4; ++r) {
                const int grow = growb + r;
                float s = 0.f;
#pragma unroll
                for (int j = 0; j < 4; ++j) {
                    const int gcol = c0 + wc + j * 16 + c16;
                    float sim = acc[i][j][r] * INV_T;
                    float e = __expf(sim - INV_T);
                    if (isdiag && grow == gcol) e = 0.f;   // diagonal mask
                    if (haspair && gcol == grow + HALF_N) {
                        __hip_atomic_store(&s_target[grow], sim, __ATOMIC_RELAXED,
                                           __HIP_MEMORY_SCOPE_AGENT);
                        __hip_atomic_store(&s_target[gcol], sim, __ATOMIC_RELAXED,
                                           __HIP_MEMORY_SCOPE_AGENT);
                    }
                    s += e;
                    cs[j] += e;
                }
                s += __shfl_xor(s, 1);
                s += __shfl_xor(s, 2);
                s += __shfl_xor(s, 4);
                s += __shfl_xor(s, 8);
                if (c16 == 0) atomicAdd(&row_sum[grow], s);
            }
        }
        if (!isdiag) {
#pragma unroll
            for (int j = 0; j < 4; ++j) {
                float s = cs[j];
                s += __shfl_xor(s, 16);
                s += __shfl_xor(s, 32);
                if (q == 0) atomicAdd(&row_sum[c0 + wc + j * 16 + c16], s);
            }
        }

        // ---- signal tile done + pop next ----
        __syncthreads();   // all waves' atomics issued (vmcnt drained here)
        if (tid == 0) {
            my_ord = __hip_atomic_fetch_add(done_cnt, 1u, __ATOMIC_RELAXED,
                                            __HIP_MEMORY_SCOPE_AGENT);
            next_t = __hip_atomic_fetch_add(tile_cnt, 1u, __ATOMIC_RELAXED,
                                            __HIP_MEMORY_SCOPE_AGENT);
        }
        __syncthreads();
        const unsigned int ord = my_ord;
        if (ord >= N_TILES - N_RED) {
            // this block completed one of the LAST 8 tiles -> do a loss slice
            if (tid == 0) {
                while (__hip_atomic_load(done_cnt, __ATOMIC_RELAXED,
                                         __HIP_MEMORY_SCOPE_AGENT) < N_TILES)
                    __builtin_amdgcn_s_sleep(1);
            }
            __syncthreads();
            const int slice = (int)(ord - (N_TILES - N_RED));   // 0..7
            const int base_row = slice * (N_ROWS / N_RED) + tid * 4;
            float rv[4], sv[4];
#pragma unroll
            for (int u = 0; u < 4; ++u) {
                rv[u] = __hip_atomic_load(&row_sum[base_row + u], __ATOMIC_RELAXED,
                                          __HIP_MEMORY_SCOPE_AGENT);
                sv[u] = __hip_atomic_load(&s_target[base_row + u], __ATOMIC_RELAXED,
                                          __HIP_MEMORY_SCOPE_AGENT);
            }
            float local = 0.f;
#pragma unroll
            for (int u = 0; u < 4; ++u)
                local += __logf(rv[u]) - sv[u];
#pragma unroll
            for (int off = 32; off; off >>= 1) local += __shfl_xor(local, off);
            __shared__ float part[4];
            if ((tid & 63) == 0) part[tid >> 6] = local;
            __syncthreads();
            if (tid == 0) {
                float bsum = part[0] + part[1] + part[2] + part[3];
                __hip_atomic_fetch_add(loss_acc, bsum, __ATOMIC_RELAXED,
                                       __HIP_MEMORY_SCOPE_AGENT);
                unsigned int f = __hip_atomic_fetch_add(fin_cnt, 1u, __ATOMIC_ACQ_REL,
                                                        __HIP_MEMORY_SCOPE_AGENT);
                if (f == N_RED - 1) {
                    float accv = __hip_atomic_load(loss_acc, __ATOMIC_RELAXED,
                                                   __HIP_MEMORY_SCOPE_AGENT);
                    out[0] = INV_T + accv * (1.0f / N_ROWS);
                }
            }
            __syncthreads();
        }
    }
}

// ---------------------------------------------------------------------------
extern "C" void kernel_launch(void* const* d_in, const int* in_sizes, int n_in,
                              void* d_out, int out_size, void* d_ws, size_t ws_size,
                              hipStream_t stream) {
    const float* feat = (const float*)d_in[0];
    float* out = (float*)d_out;
    char* ws = (char*)d_ws;

    unsigned char* fn8 = (unsigned char*)ws;                  // 8192*1024 fp8 = 8 MiB
    size_t off = (size_t)N_ROWS * D_DIM;
    float* row_sum = (float*)(ws + off);   off += N_ROWS * sizeof(float);
    float* s_target = (float*)(ws + off);  off += N_ROWS * sizeof(float);
    unsigned int* done_cnt = (unsigned int*)(ws + off);  off += sizeof(unsigned int);
    unsigned int* fin_cnt = (unsigned int*)(ws + off);   off += sizeof(unsigned int);
    float* loss_acc = (float*)(ws + off);  off += sizeof(float);
    unsigned int* tile_cnt = (unsigned int*)(ws + off);

    norm_kernel<<<N_ROWS / 4, 256, 0, stream>>>(feat, fn8, row_sum, done_cnt, fin_cnt,
                                                loss_acc, tile_cnt);
    simgemm_kernel<<<N_PERS, 256, 0, stream>>>(fn8, row_sum, s_target, done_cnt, fin_cnt,
                                               loss_acc, tile_cnt, out);
}

// Round 10
// 140.957 us; speedup vs baseline: 1.5487x; 1.2109x over previous
//
#include <hip/hip_runtime.h>
#include <hip/hip_bf16.h>

// Problem constants
#define N_ROWS 8192
#define D_DIM  1024
#define HALF_N 4096
#define N_TILES 2080             // 64*65/2 upper-triangular 128x128 tile pairs
#define N_RED  8                 // parallel loss-reduction blocks
constexpr float INV_T = 1.0f / 0.07f;   // 14.2857143 — also the fixed softmax max M

typedef __attribute__((ext_vector_type(4))) float f32x4;
typedef __attribute__((ext_vector_type(2))) long long2_;   // 16B = one ds_read_b128

// async global->LDS, 16B/lane. LDS dest is wave-uniform base + lane*16.
__device__ __forceinline__ void async_ld16(const void* g, void* lds) {
    __builtin_amdgcn_global_load_lds(
        (const __attribute__((address_space(1))) void*)g,
        (__attribute__((address_space(3))) void*)lds,
        16, 0, 0);
}

// pack 4 floats -> 4 OCP e4m3 bytes in one dword
__device__ __forceinline__ unsigned int pk_fp8x4(float a, float b, float c, float d) {
    int v = __builtin_amdgcn_cvt_pk_fp8_f32(a, b, 0, false);   // bytes 0,1
    v = __builtin_amdgcn_cvt_pk_fp8_f32(c, d, v, true);        // bytes 2,3
    return (unsigned int)v;
}

// ---------------------------------------------------------------------------
// Kernel 1: row norms + fp8 e4m3 normalized copy + zeroing of row_sum and the
// handshake cells (done_cnt, fin_cnt, loss_acc). One wave per row.
__global__ __launch_bounds__(256) void norm_kernel(const float* __restrict__ feat,
                                                   unsigned char* __restrict__ fn8,
                                                   float* __restrict__ row_sum,
                                                   unsigned int* __restrict__ done_cnt,
                                                   unsigned int* __restrict__ fin_cnt,
                                                   float* __restrict__ loss_acc) {
    const int w = threadIdx.x >> 6, lane = threadIdx.x & 63;
    const int row = blockIdx.x * 4 + w;
    if (blockIdx.x == 0 && threadIdx.x == 0) {
        *done_cnt = 0u;
        *fin_cnt = 0u;
        *loss_acc = 0.f;
    }
    const float4* src = (const float4*)(feat + (size_t)row * D_DIM);
    float4 v[4];
    float ss = 0.f;
#pragma unroll
    for (int t = 0; t < 4; ++t) {
        v[t] = src[lane + 64 * t];
        ss += v[t].x * v[t].x + v[t].y * v[t].y + v[t].z * v[t].z + v[t].w * v[t].w;
    }
#pragma unroll
    for (int off = 32; off; off >>= 1) ss += __shfl_xor(ss, off);
    float nrm = fmaxf(sqrtf(ss), 1e-8f);
    if (lane == 0) row_sum[row] = 0.f;
    const float inv = 1.0f / nrm;
    unsigned int* dst = (unsigned int*)(fn8 + (size_t)row * D_DIM);
#pragma unroll
    for (int t = 0; t < 4; ++t)
        dst[lane + 64 * t] = pk_fp8x4(v[t].x * inv, v[t].y * inv, v[t].z * inv, v[t].w * inv);
}

// ---------------------------------------------------------------------------
// Kernel 2 (r27 = r0 RESTORED + T1 XCD swizzle): SYMMETRIC triangular sim
// GEMM in FP8 (e4m3) + fixed-max exp acc + s_target extraction + fence-free
// fused loss tail. This is the measured optimum (simgemm 77.3 us, total
// 142.2-142.7) of NINE structural variants tried in rounds 1-8 (counted-vmcnt
// rings, ragged-256 8-phase, MX-scaled swap, issue-early dbuf, zero-staging,
// register ping-pong, persistent queue — ALL regressed or neutral; r21
// proved the loop scaffold-bound: halving MFMA cycles moved duration zero).
// The ONE addition vs r0: XCD-aware bijective blockIdx swizzle (2080%8==0):
// consecutive tiles share the J-indexed B-panel; per-XCD contiguous chunks
// keep those panels L2-local instead of interleaving all panels across all
// 8 XCD L2s (r0 FETCH_SIZE 90MB vs 8MB input = heavy L3 re-fetch).
__global__ __launch_bounds__(256) void simgemm_kernel(const unsigned char* __restrict__ fn8,
                                                      float* __restrict__ row_sum,
                                                      float* __restrict__ s_target,
                                                      unsigned int* __restrict__ done_cnt,
                                                      unsigned int* __restrict__ fin_cnt,
                                                      float* __restrict__ loss_acc,
                                                      float* __restrict__ out) {
    __shared__ __align__(16) unsigned char As[128 * 64];   // 8 KiB
    __shared__ __align__(16) unsigned char Bs[128 * 64];   // 8 KiB
    // T1: XCD-aware bijective swizzle (8 XCDs x 260 contiguous tiles)
    const int t = (blockIdx.x & 7) * (N_TILES / 8) + (blockIdx.x >> 3);
    // triangular decode: t -> (I,J), I<=J
    int a = (int)((sqrtf(8.f * (float)t + 1.f) - 1.f) * 0.5f);
    while ((a + 1) * (a + 2) / 2 <= t) ++a;
    while (a * (a + 1) / 2 > t) --a;
    const int I = t - a * (a + 1) / 2;   // row-tile index (<= J)
    const int J = a;                     // col-tile index
    const int r0 = I * 128, c0 = J * 128;
    const bool isdiag = (I == J);
    const bool haspair = (J == I + 32);  // contains sim[i, i+4096] for rows in I

    const int tid = threadIdx.x;
    const int w = tid >> 6, lane = tid & 63;
    const int q = lane >> 4, c16 = lane & 15;
    const int wr = (w >> 1) * 64;  // wave's row base within tile
    const int wc = (w & 1) * 64;   // wave's col base within tile
    const int wr4 = (w >> 1) * 4;  // wave's A chunk base (16-row chunks)
    const int wc4 = (w & 1) * 4;   // wave's B chunk base
    // staging: wave w stages chunks 2w, 2w+1 (rows w*32 .. w*32+31).
    const int srow = lane >> 2;                               // row within chunk
    const int skoff = ((lane & 3) ^ ((srow >> 1) & 3)) * 16;  // swizzled unit byte offset
    // fragment read byte offset within a chunk (kt-invariant): logical unit q
    // of row c16 sits at physical unit q ^ f(c16), f(r) = (r>>1)&3.
    const int lfo = c16 * 64 + ((q ^ ((c16 >> 1) & 3)) * 16);

    const unsigned char* pa0 = fn8 + (size_t)(r0 + w * 32 + srow) * D_DIM + skoff;
    const unsigned char* pa1 = pa0 + 16 * D_DIM;
    const unsigned char* pb0 = fn8 + (size_t)(c0 + w * 32 + srow) * D_DIM + skoff;
    const unsigned char* pb1 = pb0 + 16 * D_DIM;

    f32x4 acc[4][4];
#pragma unroll
    for (int i = 0; i < 4; ++i)
#pragma unroll
        for (int j = 0; j < 4; ++j) acc[i][j] = (f32x4){0.f, 0.f, 0.f, 0.f};

    for (int kt = 0; kt < 16; ++kt) {
        __syncthreads();  // previous window's reads done before overwrite
        async_ld16(pa0, (void*)&As[(w * 2 + 0) * 1024]);
        async_ld16(pa1, (void*)&As[(w * 2 + 1) * 1024]);
        async_ld16(pb0, (void*)&Bs[(w * 2 + 0) * 1024]);
        async_ld16(pb1, (void*)&Bs[(w * 2 + 1) * 1024]);
        pa0 += 64; pa1 += 64; pb0 += 64; pb1 += 64;
        __syncthreads();  // drains vmcnt(0): staging visible

        long2_ af[4], bf[4];
#pragma unroll
        for (int i = 0; i < 4; ++i)
            af[i] = *(const long2_*)&As[(wr4 + i) * 1024 + lfo];
#pragma unroll
        for (int j = 0; j < 4; ++j)
            bf[j] = *(const long2_*)&Bs[(wc4 + j) * 1024 + lfo];
#pragma unroll
        for (int i = 0; i < 4; ++i)
#pragma unroll
            for (int j = 0; j < 4; ++j) {
                acc[i][j] = __builtin_amdgcn_mfma_f32_16x16x32_fp8_fp8(
                    af[i].x, bf[j].x, acc[i][j], 0, 0, 0);
                acc[i][j] = __builtin_amdgcn_mfma_f32_16x16x32_fp8_fp8(
                    af[i].y, bf[j].y, acc[i][j], 0, 0, 0);
            }
    }

    // epilogue: e = exp(sim - M); rows-in-I sums + (I<J) cols-in-J sums.
    float cs[4] = {0.f, 0.f, 0.f, 0.f};   // per-j column partial sums
#pragma unroll
    for (int i = 0; i < 4; ++i) {
        const int growb = r0 + wr + i * 16 + q * 4;
#pragma unroll
        for (int r = 0; r < 4; ++r) {
            const int grow = growb + r;
            float s = 0.f;
#pragma unroll
            for (int j = 0; j < 4; ++j) {
                const int gcol = c0 + wc + j * 16 + c16;
                float sim = acc[i][j][r] * INV_T;
                float e = __expf(sim - INV_T);
                if (isdiag && grow == gcol) e = 0.f;   // diagonal mask
                if (haspair && gcol == grow + HALF_N) {
                    __hip_atomic_store(&s_target[grow], sim, __ATOMIC_RELAXED,
                                       __HIP_MEMORY_SCOPE_AGENT);
                    __hip_atomic_store(&s_target[gcol], sim, __ATOMIC_RELAXED,
                                       __HIP_MEMORY_SCOPE_AGENT);
                }
                s += e;
                cs[j] += e;
            }
            // row path: reduce over the 16 col-lanes of the quad
            s += __shfl_xor(s, 1);
            s += __shfl_xor(s, 2);
            s += __shfl_xor(s, 4);
            s += __shfl_xor(s, 8);
            if (c16 == 0) atomicAdd(&row_sum[grow], s);
        }
    }
    if (!isdiag) {
        // col path: reduce each cs[j] across the 4 quads, one atomic/column
#pragma unroll
        for (int j = 0; j < 4; ++j) {
            float s = cs[j];
            s += __shfl_xor(s, 16);
            s += __shfl_xor(s, 32);
            if (q == 0) atomicAdd(&row_sum[c0 + wc + j * 16 + c16], s);
        }
    }

    // ---- fence-free fused loss tail, 8-way parallel ----
    __syncthreads();   // all waves' vmem drained (compiler emits vmcnt(0) here)
    __shared__ unsigned int my_ord;
    if (tid == 0)
        my_ord = __hip_atomic_fetch_add(done_cnt, 1u, __ATOMIC_RELAXED,
                                        __HIP_MEMORY_SCOPE_AGENT);
    __syncthreads();
    const unsigned int ord = my_ord;
    if (ord >= N_TILES - N_RED) {
        // wait until ALL 2080 blocks have signalled (their sums are in).
        if (tid == 0) {
            while (__hip_atomic_load(done_cnt, __ATOMIC_RELAXED,
                                     __HIP_MEMORY_SCOPE_AGENT) < N_TILES)
                __builtin_amdgcn_s_sleep(1);
        }
        __syncthreads();
        const int slice = (int)(ord - (N_TILES - N_RED));   // 0..7
        const int base_row = slice * (N_ROWS / N_RED) + tid * 4;
        float rv[4], sv[4];
#pragma unroll
        for (int u = 0; u < 4; ++u) {
            rv[u] = __hip_atomic_load(&row_sum[base_row + u], __ATOMIC_RELAXED,
                                      __HIP_MEMORY_SCOPE_AGENT);
            sv[u] = __hip_atomic_load(&s_target[base_row + u], __ATOMIC_RELAXED,
                                      __HIP_MEMORY_SCOPE_AGENT);
        }
        float local = 0.f;
#pragma unroll
        for (int u = 0; u < 4; ++u)
            local += __logf(rv[u]) - sv[u];
#pragma unroll
        for (int off = 32; off; off >>= 1) local += __shfl_xor(local, off);
        __shared__ float part[4];
        if ((tid & 63) == 0) part[tid >> 6] = local;
        __syncthreads();
        if (tid == 0) {
            float bsum = part[0] + part[1] + part[2] + part[3];
            __hip_atomic_fetch_add(loss_acc, bsum, __ATOMIC_RELAXED,
                                   __HIP_MEMORY_SCOPE_AGENT);
            unsigned int f = __hip_atomic_fetch_add(fin_cnt, 1u, __ATOMIC_ACQ_REL,
                                                    __HIP_MEMORY_SCOPE_AGENT);
            if (f == N_RED - 1) {
                float accv = __hip_atomic_load(loss_acc, __ATOMIC_RELAXED,
                                               __HIP_MEMORY_SCOPE_AGENT);
                out[0] = INV_T + accv * (1.0f / N_ROWS);
            }
        }
    }
}

// ---------------------------------------------------------------------------
extern "C" void kernel_launch(void* const* d_in, const int* in_sizes, int n_in,
                              void* d_out, int out_size, void* d_ws, size_t ws_size,
                              hipStream_t stream) {
    const float* feat = (const float*)d_in[0];
    float* out = (float*)d_out;
    char* ws = (char*)d_ws;

    unsigned char* fn8 = (unsigned char*)ws;                  // 8192*1024 fp8 = 8 MiB
    size_t off = (size_t)N_ROWS * D_DIM;
    float* row_sum = (float*)(ws + off);   off += N_ROWS * sizeof(float);
    float* s_target = (float*)(ws + off);  off += N_ROWS * sizeof(float);
    unsigned int* done_cnt = (unsigned int*)(ws + off);  off += sizeof(unsigned int);
    unsigned int* fin_cnt = (unsigned int*)(ws + off);   off += sizeof(unsigned int);
    float* loss_acc = (float*)(ws + off);

    norm_kernel<<<N_ROWS / 4, 256, 0, stream>>>(feat, fn8, row_sum, done_cnt, fin_cnt, loss_acc);
    simgemm_kernel<<<N_TILES, 256, 0, stream>>>(fn8, row_sum, s_target, done_cnt, fin_cnt, loss_acc, out);
}